// Round 3
// baseline (87.798 us; speedup 1.0000x reference)
//
#include <hip/hip_runtime.h>

#define NROWS 4096
#define DIM 128
#define PCLS 1024
#define NPAIR 6144
#define MARGIN 1.0f
#define EPS 1e-6f
#define NBLK 512

typedef __attribute__((ext_vector_type(8))) short bf16x8;
typedef __attribute__((ext_vector_type(4))) float f32x4;

union FragU { uint4 u; bf16x8 v; };

__device__ __forceinline__ unsigned short f2bf(float f) {
    unsigned int b = __float_as_uint(f);
    b = (b + 0x7FFFu + ((b >> 16) & 1u)) >> 16;
    return (unsigned short)b;
}

// one wave per row: norms (f32) + bf16 conversion; block 0 zeroes the counter
__global__ void prep_kernel(const float* __restrict__ x,
                            unsigned short* __restrict__ xbf,
                            float* __restrict__ norms,
                            int* __restrict__ counter) {
    if (blockIdx.x == 0 && threadIdx.x == 0) *counter = 0;
    int row = blockIdx.x * 4 + (threadIdx.x >> 6);
    int l = threadIdx.x & 63;
    float2 v = *reinterpret_cast<const float2*>(x + row * DIM + 2 * l);
    unsigned int packed = (unsigned int)f2bf(v.x) | ((unsigned int)f2bf(v.y) << 16);
    *reinterpret_cast<unsigned int*>(xbf + row * DIM + 2 * l) = packed;
    float s = v.x * v.x + v.y * v.y;
    #pragma unroll
    for (int m = 1; m < 64; m <<= 1) s += __shfl_xor(s, m, 64);
    if (l == 0) norms[row] = s;
}

// Gram tiles via bf16 MFMA + fused exp epilogue + positive-pair extraction
// + last-block tail reduction.
// grid: 32 row-blocks (128 rows) x 16 col-splits (256 cols) = 512 blocks, 512 thr.
__launch_bounds__(512, 4)
__global__ void main_kernel(const unsigned short* __restrict__ xbf,
                            const float* __restrict__ norms,
                            float* __restrict__ partial,
                            float* __restrict__ posD,
                            int* __restrict__ counter,
                            float* __restrict__ out) {
    __shared__ __align__(16) unsigned short lds[256 * DIM]; // 64 KB, 256 staged cols
    const int t = threadIdx.x;
    const int w = t >> 6;
    const int l = t & 63;
    const int rb = blockIdx.x >> 4;
    const int cs = blockIdx.x & 15;
    const int rbase = rb * 128 + w * 16;   // this wave's 16 rows
    const int cbase = cs * 256;
    const int lg = l >> 4;                 // k-group (0..3)
    const int lr = l & 15;                 // frag row/col index

    // A fragments (16 rows x 128 k) in registers, straight from global
    FragU afr[4];
    const char* abase = (const char*)xbf + (size_t)(rbase + lr) * 256 + lg * 16;
    #pragma unroll
    for (int s = 0; s < 4; ++s)
        afr[s].u = *reinterpret_cast<const uint4*>(abase + s * 64);

    // stage 256 cols x 128 k (bf16) with XOR-swizzled LDS layout
    #pragma unroll
    for (int it = 0; it < 8; ++it) {
        int lin = it * 8192 + t * 16;
        int col = lin >> 8;
        int inner = lin & 255;
        uint4 v = *reinterpret_cast<const uint4*>(
            (const char*)xbf + (size_t)(cbase + col) * 256 + inner);
        *reinterpret_cast<uint4*>(
            (char*)lds + col * 256 + (inner ^ ((col & 7) << 4))) = v;
    }

    float ni[4];
    #pragma unroll
    for (int rr = 0; rr < 4; ++rr) ni[rr] = norms[rbase + lg * 4 + rr];

    __syncthreads();

    float accS[4] = {0.f, 0.f, 0.f, 0.f};

    #pragma unroll 4
    for (int tile = 0; tile < 16; ++tile) {
        const int lcol = tile * 16 + lr;
        const int jglob = cbase + lcol;
        const float nj = norms[jglob];
        const char* bbase = (const char*)lds + lcol * 256;
        const int xr = (lcol & 7) << 4;
        f32x4 acc = {0.f, 0.f, 0.f, 0.f};
        #pragma unroll
        for (int s = 0; s < 4; ++s) {
            FragU bu;
            int inner = s * 64 + lg * 16;
            bu.u = *reinterpret_cast<const uint4*>(bbase + (inner ^ xr));
            acc = __builtin_amdgcn_mfma_f32_16x16x32_bf16(afr[s].v, bu.v, acc, 0, 0, 0);
        }
        const bool diag = (cbase + tile * 16) == rbase;  // wave-uniform
        if (!diag) {
            #pragma unroll
            for (int rr = 0; rr < 4; ++rr) {
                float nn = ni[rr] + nj;
                float d2 = fmaf(-2.0f, acc[rr], nn);
                float d = __builtin_amdgcn_sqrtf(fmaxf(d2, 0.f) + EPS);
                accS[rr] += __expf(MARGIN - d);
            }
        } else {
            #pragma unroll
            for (int rr = 0; rr < 4; ++rr) {
                int a = lg * 4 + rr;               // local row 0..15
                int b = lr;                        // local col 0..15
                float nn = ni[rr] + nj;
                float d2 = fmaf(-2.0f, acc[rr], nn);
                float d = __builtin_amdgcn_sqrtf(fmaxf(d2, 0.f) + EPS);
                bool same = (a >> 2) == (b >> 2);
                accS[rr] += same ? 0.f : __expf(MARGIN - d);
                if (same && a < b) {
                    int i = a & 3, j = b & 3;
                    int idx = i * (7 - i) / 2 + (j - i - 1);
                    int cls = (rbase + a) >> 2;
                    posD[cls * 6 + idx] = d;
                }
            }
        }
    }
    // reduce over the 16 col-lanes (lr varies within xor masks 1..8)
    #pragma unroll
    for (int rr = 0; rr < 4; ++rr) {
        #pragma unroll
        for (int m = 1; m < 16; m <<= 1) accS[rr] += __shfl_xor(accS[rr], m, 64);
    }
    if (lr == 0) {
        #pragma unroll
        for (int rr = 0; rr < 4; ++rr)
            partial[cs * NROWS + rbase + lg * 4 + rr] = accS[rr];
    }

    // ---- last-block tail: S per row, J per pair, relu^2, mean ----
    __threadfence();                       // release partial/posD (agent scope)
    __shared__ int lastFlag;
    if (t == 0) lastFlag = (atomicAdd(counter, 1) == NBLK - 1);
    __syncthreads();
    if (!lastFlag) return;
    __threadfence();                       // acquire: invalidate caches before reads

    float acc2 = 0.f;
    #pragma unroll
    for (int cc = 0; cc < 2; ++cc) {
        int c = t + cc * 512;              // class 0..1023, coalesced float4 reads
        float S0 = 0.f, S1 = 0.f, S2 = 0.f, S3 = 0.f;
        #pragma unroll
        for (int sp = 0; sp < 16; ++sp) {
            float4 v = *reinterpret_cast<const float4*>(partial + sp * NROWS + 4 * c);
            S0 += v.x; S1 += v.y; S2 += v.z; S3 += v.w;
        }
        float Sa[4] = {S0, S1, S2, S3};
        const int II[6] = {0, 0, 0, 1, 1, 2};
        const int JJ[6] = {1, 2, 3, 2, 3, 3};
        #pragma unroll
        for (int p = 0; p < 6; ++p) {
            float d = posD[c * 6 + p];
            float J = __logf(Sa[II[p]] + Sa[JJ[p]]) + d;
            float r = fmaxf(J, 0.f);
            acc2 += r * r;
        }
    }
    #pragma unroll
    for (int m = 1; m < 64; m <<= 1) acc2 += __shfl_xor(acc2, m, 64);
    __shared__ float red[8];
    if (l == 0) red[w] = acc2;
    __syncthreads();
    if (t == 0) {
        float v = red[0] + red[1] + red[2] + red[3] + red[4] + red[5] + red[6] + red[7];
        out[0] = v * (1.0f / (2.0f * (float)NPAIR));
    }
}

extern "C" void kernel_launch(void* const* d_in, const int* in_sizes, int n_in,
                              void* d_out, int out_size, void* d_ws, size_t ws_size,
                              hipStream_t stream) {
    const float* x = (const float*)d_in[0];
    char* ws = (char*)d_ws;
    unsigned short* xbf = (unsigned short*)ws;                        // 1 MB
    float* norms = (float*)(ws + 1048576);                            // 16 KB
    float* partial = (float*)(ws + 1048576 + 16384);                  // 16*4096 f32 = 256 KB
    float* posD = (float*)(ws + 1048576 + 16384 + 262144);            // 24 KB
    int* counter = (int*)(ws + 1048576 + 16384 + 262144 + 24576);     // 4 B
    float* out = (float*)d_out;

    hipLaunchKernelGGL(prep_kernel, dim3(NROWS / 4), dim3(256), 0, stream, x, xbf, norms, counter);
    hipLaunchKernelGGL(main_kernel, dim3(NBLK), dim3(512), 0, stream, xbf, norms, partial, posD, counter, out);
}

// Round 4
// 24.599 us; speedup vs baseline: 3.5692x; 3.5692x over previous
//
#include <hip/hip_runtime.h>

#define NROWS 4096
#define DIM 128
#define PCLS 1024
#define NPAIR 6144
#define MARGIN 1.0f
#define EPS 1e-6f

typedef __attribute__((ext_vector_type(8))) short bf16x8;
typedef __attribute__((ext_vector_type(4))) float f32x4;

union FragU { uint4 u; bf16x8 v; };

__device__ __forceinline__ unsigned short f2bf(float f) {
    unsigned int b = __float_as_uint(f);
    b = (b + 0x7FFFu + ((b >> 16) & 1u)) >> 16;
    return (unsigned short)b;
}

// one wave per row: norms (f32) + bf16 conversion
__global__ void prep_kernel(const float* __restrict__ x,
                            unsigned short* __restrict__ xbf,
                            float* __restrict__ norms) {
    int row = blockIdx.x * 4 + (threadIdx.x >> 6);
    int l = threadIdx.x & 63;
    float2 v = *reinterpret_cast<const float2*>(x + row * DIM + 2 * l);
    unsigned int packed = (unsigned int)f2bf(v.x) | ((unsigned int)f2bf(v.y) << 16);
    *reinterpret_cast<unsigned int*>(xbf + row * DIM + 2 * l) = packed;
    float s = v.x * v.x + v.y * v.y;
    #pragma unroll
    for (int m = 1; m < 64; m <<= 1) s += __shfl_xor(s, m, 64);
    if (l == 0) norms[row] = s;
}

// Gram tiles via bf16 MFMA + fused exp epilogue + positive-pair extraction.
// grid: 32 row-blocks (128 rows) x 16 col-splits (256 cols) = 512 blocks, 512 thr.
__launch_bounds__(512, 4)
__global__ void main_kernel(const unsigned short* __restrict__ xbf,
                            const float* __restrict__ norms,
                            float* __restrict__ partial,
                            float* __restrict__ posD) {
    __shared__ __align__(16) unsigned short lds[256 * DIM]; // 64 KB, 256 staged cols
    const int t = threadIdx.x;
    const int w = t >> 6;
    const int l = t & 63;
    const int rb = blockIdx.x >> 4;
    const int cs = blockIdx.x & 15;
    const int rbase = rb * 128 + w * 16;   // this wave's 16 rows
    const int cbase = cs * 256;
    const int lg = l >> 4;                 // k-group (0..3)
    const int lr = l & 15;                 // frag row/col index

    // A fragments (16 rows x 128 k) in registers, straight from global
    FragU afr[4];
    const char* abase = (const char*)xbf + (size_t)(rbase + lr) * 256 + lg * 16;
    #pragma unroll
    for (int s = 0; s < 4; ++s)
        afr[s].u = *reinterpret_cast<const uint4*>(abase + s * 64);

    // prefetch ALL column norms for this wave's lr lane (latency hidden by
    // the staging + barrier below); statically indexed via full unroll later
    float njv[16];
    #pragma unroll
    for (int tile = 0; tile < 16; ++tile)
        njv[tile] = norms[cbase + tile * 16 + lr];

    float ni[4];
    #pragma unroll
    for (int rr = 0; rr < 4; ++rr) ni[rr] = norms[rbase + lg * 4 + rr];

    // stage 256 cols x 128 k (bf16) with XOR-swizzled LDS layout
    #pragma unroll
    for (int it = 0; it < 8; ++it) {
        int lin = it * 8192 + t * 16;
        int col = lin >> 8;
        int inner = lin & 255;
        uint4 v = *reinterpret_cast<const uint4*>(
            (const char*)xbf + (size_t)(cbase + col) * 256 + inner);
        *reinterpret_cast<uint4*>(
            (char*)lds + col * 256 + (inner ^ ((col & 7) << 4))) = v;
    }

    __syncthreads();

    float accS[4] = {0.f, 0.f, 0.f, 0.f};

    #pragma unroll
    for (int tile = 0; tile < 16; ++tile) {
        const int lcol = tile * 16 + lr;
        const float nj = njv[tile];
        const char* bbase = (const char*)lds + lcol * 256;
        const int xr = (lcol & 7) << 4;
        f32x4 acc = {0.f, 0.f, 0.f, 0.f};
        #pragma unroll
        for (int s = 0; s < 4; ++s) {
            FragU bu;
            int inner = s * 64 + lg * 16;
            bu.u = *reinterpret_cast<const uint4*>(bbase + (inner ^ xr));
            acc = __builtin_amdgcn_mfma_f32_16x16x32_bf16(afr[s].v, bu.v, acc, 0, 0, 0);
        }
        const bool diag = (cbase + tile * 16) == rbase;  // wave-uniform
        if (!diag) {
            #pragma unroll
            for (int rr = 0; rr < 4; ++rr) {
                float nn = ni[rr] + nj;
                float d2 = fmaf(-2.0f, acc[rr], nn);
                float d = __builtin_amdgcn_sqrtf(fmaxf(d2, 0.f) + EPS);
                accS[rr] += __expf(MARGIN - d);
            }
        } else {
            #pragma unroll
            for (int rr = 0; rr < 4; ++rr) {
                int a = lg * 4 + rr;               // local row 0..15
                int b = lr;                        // local col 0..15
                float nn = ni[rr] + nj;
                float d2 = fmaf(-2.0f, acc[rr], nn);
                float d = __builtin_amdgcn_sqrtf(fmaxf(d2, 0.f) + EPS);
                bool same = (a >> 2) == (b >> 2);
                accS[rr] += same ? 0.f : __expf(MARGIN - d);
                if (same && a < b) {
                    int i = a & 3, j = b & 3;
                    int idx = i * (7 - i) / 2 + (j - i - 1);
                    int cls = (rbase + a) >> 2;
                    posD[cls * 6 + idx] = d;
                }
            }
        }
    }
    // reduce over the 16 col-lanes (lr varies within xor masks 1..8)
    #pragma unroll
    for (int rr = 0; rr < 4; ++rr) {
        #pragma unroll
        for (int m = 1; m < 16; m <<= 1) accS[rr] += __shfl_xor(accS[rr], m, 64);
    }
    if (lr == 0) {
        #pragma unroll
        for (int rr = 0; rr < 4; ++rr)
            partial[cs * NROWS + rbase + lg * 4 + rr] = accS[rr];
    }
}

// single block: S = sum of col-split partials, J per pair, relu^2, mean
__global__ void tail_kernel(const float* __restrict__ partial,
                            const float* __restrict__ posD,
                            float* __restrict__ out) {
    const int c = threadIdx.x;    // class 0..1023
    float S[4] = {0.f, 0.f, 0.f, 0.f};
    #pragma unroll
    for (int sp = 0; sp < 16; ++sp) {
        float4 v = *reinterpret_cast<const float4*>(partial + sp * NROWS + 4 * c);
        S[0] += v.x; S[1] += v.y; S[2] += v.z; S[3] += v.w;
    }
    const int II[6] = {0, 0, 0, 1, 1, 2};
    const int JJ[6] = {1, 2, 3, 2, 3, 3};
    float acc = 0.f;
    #pragma unroll
    for (int p = 0; p < 6; ++p) {
        float d = posD[c * 6 + p];
        float J = __logf(S[II[p]] + S[JJ[p]]) + d;
        float r = fmaxf(J, 0.f);
        acc += r * r;
    }
    // block reduce 1024 -> 1
    #pragma unroll
    for (int m = 1; m < 64; m <<= 1) acc += __shfl_xor(acc, m, 64);
    __shared__ float red[16];
    if ((c & 63) == 0) red[c >> 6] = acc;
    __syncthreads();
    if (c < 64) {
        float v = (c < 16) ? red[c] : 0.f;
        #pragma unroll
        for (int m = 1; m < 16; m <<= 1) v += __shfl_xor(v, m, 64);
        if (c == 0) out[0] = v * (1.0f / (2.0f * (float)NPAIR));
    }
}

extern "C" void kernel_launch(void* const* d_in, const int* in_sizes, int n_in,
                              void* d_out, int out_size, void* d_ws, size_t ws_size,
                              hipStream_t stream) {
    const float* x = (const float*)d_in[0];
    char* ws = (char*)d_ws;
    unsigned short* xbf = (unsigned short*)ws;                        // 1 MB
    float* norms = (float*)(ws + 1048576);                            // 16 KB
    float* partial = (float*)(ws + 1048576 + 16384);                  // 16*4096 f32 = 256 KB
    float* posD = (float*)(ws + 1048576 + 16384 + 262144);            // 24 KB
    float* out = (float*)d_out;

    hipLaunchKernelGGL(prep_kernel, dim3(NROWS / 4), dim3(256), 0, stream, x, xbf, norms);
    hipLaunchKernelGGL(main_kernel, dim3(512), dim3(512), 0, stream, xbf, norms, partial, posD);
    hipLaunchKernelGGL(tail_kernel, dim3(1), dim3(1024), 0, stream, partial, posD, out);
}